// Round 1
// baseline (772.031 us; speedup 1.0000x reference)
//
#include <hip/hip_runtime.h>
#include <math.h>

typedef __bf16 bf16x8 __attribute__((ext_vector_type(8)));
typedef float f32x4 __attribute__((ext_vector_type(4)));
typedef unsigned short us8 __attribute__((ext_vector_type(8)));

#define B_ 2
#define L_ 2048
#define D_ 2048
#define H_ 16
#define DH 128

__device__ __forceinline__ unsigned short f2b(float f) {
  union { float f; unsigned u; } v; v.f = f;
  unsigned u = v.u;
  return (unsigned short)((u + 0x7fffu + ((u >> 16) & 1u)) >> 16);
}
__device__ __forceinline__ float b2f(unsigned short h) {
  union { unsigned u; float f; } v; v.u = ((unsigned)h) << 16;
  return v.f;
}

#define GLD16(g, l) __builtin_amdgcn_global_load_lds(                          \
    (const __attribute__((address_space(1))) void*)(g),                        \
    (__attribute__((address_space(3))) void*)(l), 16, 0, 0)

// ---------------- fp32 -> bf16 convert ----------------
__global__ void f32_to_bf16(const float* __restrict__ in,
                            unsigned short* __restrict__ out, int n4) {
  int i = blockIdx.x * blockDim.x + threadIdx.x;
  const int stride = gridDim.x * blockDim.x;
  for (; i < n4; i += stride) {
    const float4 v = ((const float4*)in)[i];
    ushort4 o;
    o.x = f2b(v.x); o.y = f2b(v.y); o.z = f2b(v.z); o.w = f2b(v.w);
    ((ushort4*)out)[i] = o;
  }
}

// ---------------- GEMM: C[m,n] = sum_k A[m,k]*B[n,k]  (both row-major, K-contig) ----------------
// 128x128 tile, BK=32, 4 waves (2x2 of 64x64), m97 structure.
template <bool OUT_BF16>
__global__ __launch_bounds__(256)
void gemm_bt(const unsigned short* __restrict__ A,
             const unsigned short* __restrict__ Bm,
             void* __restrict__ Cv, int M, int N, int K) {
  __shared__ unsigned short lA[128 * 32];
  __shared__ unsigned short lB[128 * 32];
  const int tid = threadIdx.x;
  const int wave = tid >> 6, lane = tid & 63;
  const int lo = lane & 15, hi = lane >> 4;
  const int wm = (wave >> 1) * 64, wn = (wave & 1) * 64;
  const int bm = blockIdx.y, bn = blockIdx.x;
  f32x4 acc[4][4] = {};
  const long aBase = (long)bm * 128 * K;
  const long bBase = (long)bn * 128 * K;
  for (int k0 = 0; k0 < K; k0 += 32) {
    __syncthreads();
#pragma unroll
    for (int j = 0; j < 2; ++j) {
      const int c = j * 256 + tid;
      const int row = c >> 2, cq = c & 3;
      const int lbase = (j * 256 + wave * 64) * 8;  // halves; wave-uniform
      GLD16(A + aBase + (long)row * K + k0 + cq * 8, &lA[lbase]);
      GLD16(Bm + bBase + (long)row * K + k0 + cq * 8, &lB[lbase]);
    }
    __syncthreads();
    bf16x8 af[4], bfr[4];
#pragma unroll
    for (int mi = 0; mi < 4; ++mi)
      af[mi] = *(const bf16x8*)&lA[(wm + mi * 16 + lo) * 32 + hi * 8];
#pragma unroll
    for (int ni = 0; ni < 4; ++ni)
      bfr[ni] = *(const bf16x8*)&lB[(wn + ni * 16 + lo) * 32 + hi * 8];
#pragma unroll
    for (int mi = 0; mi < 4; ++mi)
#pragma unroll
      for (int ni = 0; ni < 4; ++ni)
        acc[mi][ni] = __builtin_amdgcn_mfma_f32_16x16x32_bf16(
            af[mi], bfr[ni], acc[mi][ni], 0, 0, 0);
  }
  const int r0 = bm * 128 + wm, c0 = bn * 128 + wn;
#pragma unroll
  for (int mi = 0; mi < 4; ++mi) {
#pragma unroll
    for (int r = 0; r < 4; ++r) {
      const long row = r0 + mi * 16 + hi * 4 + r;
#pragma unroll
      for (int ni = 0; ni < 4; ++ni) {
        const int col = c0 + ni * 16 + lo;
        if (OUT_BF16)
          ((unsigned short*)Cv)[row * N + col] = f2b(acc[mi][ni][r]);
        else
          ((float*)Cv)[row * N + col] = acc[mi][ni][r];
      }
    }
  }
}

// ---------------- RoPE (interleaved pairs) + scatter to [B,H,L,dh]; Q scaled by 1/sqrt(dh) ----------------
__global__ void rope_qk(const unsigned short* __restrict__ qkv,
                        unsigned short* __restrict__ Qo,
                        unsigned short* __restrict__ Ko) {
  const int idx = blockIdx.x * 256 + threadIdx.x;  // B*H*L*64 threads
  const int i = idx & 63;
  const int l = (idx >> 6) & (L_ - 1);
  const int h = (idx >> 17) & (H_ - 1);
  const int b = idx >> 21;
  const float invf = exp2f(-(float)i * 0.20762050593045077f);  // log2(10000)/64
  const float ang = (float)l * invf;
  float sn, cs;
  sincosf(ang, &sn, &cs);
  const long base = ((long)b * L_ + l) * (3 * D_) + h * DH + 2 * i;
  const unsigned qin = *(const unsigned*)&qkv[base];
  const unsigned kin = *(const unsigned*)&qkv[base + D_];
  const float q0 = b2f((unsigned short)qin), q1 = b2f((unsigned short)(qin >> 16));
  const float k0 = b2f((unsigned short)kin), k1 = b2f((unsigned short)(kin >> 16));
  const float sc = 0.08838834764831845f;  // 1/sqrt(128)
  const float qo0 = (q0 * cs - q1 * sn) * sc, qo1 = (q1 * cs + q0 * sn) * sc;
  const float ko0 = (k0 * cs - k1 * sn), ko1 = (k1 * cs + k0 * sn);
  const long oo = ((long)(b * H_ + h) * L_ + l) * DH + 2 * i;
  *(unsigned*)&Qo[oo] = (unsigned)f2b(qo0) | ((unsigned)f2b(qo1) << 16);
  *(unsigned*)&Ko[oo] = (unsigned)f2b(ko0) | ((unsigned)f2b(ko1) << 16);
}

// ---------------- V transpose: qkv V-part [B,L,H,dh] -> Vt [B,H,dh,L] ----------------
__global__ __launch_bounds__(256)
void v_transpose(const unsigned short* __restrict__ qkv,
                 unsigned short* __restrict__ Vt) {
  const int lblk = blockIdx.x;  // L/64
  const int bh = blockIdx.y;    // B*H
  const int b = bh >> 4, h = bh & 15;
  __shared__ unsigned short tile[64 * 137];
  const int tid = threadIdx.x;
  const int l0 = lblk * 64;
#pragma unroll
  for (int j = 0; j < 4; ++j) {
    const int c = j * 256 + tid;
    const int row = c >> 4, col8 = c & 15;
    const us8 v = *(const us8*)&qkv[((long)b * L_ + l0 + row) * (3 * D_) +
                                    2 * D_ + h * DH + col8 * 8];
    unsigned short* dst = &tile[row * 137 + col8 * 8];
#pragma unroll
    for (int e = 0; e < 8; ++e) dst[e] = v[e];
  }
  __syncthreads();
#pragma unroll
  for (int j = 0; j < 4; ++j) {
    const int c = j * 256 + tid;
    const int d = c >> 3, l8 = c & 7;
    us8 v;
#pragma unroll
    for (int e = 0; e < 8; ++e) v[e] = tile[(l8 * 8 + e) * 137 + d];
    *(us8*)&Vt[((long)bh * DH + d) * L_ + l0 + l8 * 8] = v;
  }
}

// ---------------- causal flash attention ----------------
// 4 independent waves/block; each wave: 16 q-rows, KV-block 32, dh=128.
__global__ __launch_bounds__(256)
void flash_attn(const unsigned short* __restrict__ Q,
                const unsigned short* __restrict__ Kb,
                const unsigned short* __restrict__ Vt,
                unsigned short* __restrict__ Y) {
  const int qb = blockIdx.x;
  const int h = blockIdx.y;
  const int b = blockIdx.z;
  const int wave = threadIdx.x >> 6, lane = threadIdx.x & 63;
  const int lo = lane & 15, hi = lane >> 4;
  const int q0 = qb * 64 + wave * 16;
  const long hoff = ((long)(b * H_ + h)) * L_ * DH;
  const unsigned short* Qh = Q + hoff;
  const unsigned short* Kh = Kb + hoff;
  const unsigned short* Vh = Vt + hoff;  // [dh][L]
  __shared__ unsigned short pl[4][16 * 72];
  unsigned short* plw = &pl[wave][0];
  bf16x8 qf[4];
#pragma unroll
  for (int s = 0; s < 4; ++s)
    qf[s] = *(const bf16x8*)&Qh[(long)(q0 + lo) * DH + s * 32 + hi * 8];
  float m[4], lsum[4];
  f32x4 yacc[8] = {};
#pragma unroll
  for (int r = 0; r < 4; ++r) { m[r] = -INFINITY; lsum[r] = 0.f; }
  for (int kv0 = 0; kv0 < q0 + 16; kv0 += 32) {
    f32x4 s0 = {}, s1 = {};
#pragma unroll
    for (int s = 0; s < 4; ++s) {
      const bf16x8 kf0 = *(const bf16x8*)&Kh[(long)(kv0 + lo) * DH + s * 32 + hi * 8];
      const bf16x8 kf1 = *(const bf16x8*)&Kh[(long)(kv0 + 16 + lo) * DH + s * 32 + hi * 8];
      s0 = __builtin_amdgcn_mfma_f32_16x16x32_bf16(qf[s], kf0, s0, 0, 0, 0);
      s1 = __builtin_amdgcn_mfma_f32_16x16x32_bf16(qf[s], kf1, s1, 0, 0, 0);
    }
    if (kv0 + 31 > q0) {  // diagonal block: causal mask
#pragma unroll
      for (int r = 0; r < 4; ++r) {
        const int qg = q0 + hi * 4 + r;
        if (kv0 + lo > qg) s0[r] = -INFINITY;
        if (kv0 + 16 + lo > qg) s1[r] = -INFINITY;
      }
    }
    float alpha[4];
#pragma unroll
    for (int r = 0; r < 4; ++r) {
      float rm = fmaxf(s0[r], s1[r]);
      rm = fmaxf(rm, __shfl_xor(rm, 1));
      rm = fmaxf(rm, __shfl_xor(rm, 2));
      rm = fmaxf(rm, __shfl_xor(rm, 4));
      rm = fmaxf(rm, __shfl_xor(rm, 8));
      const float mn = fmaxf(m[r], rm);
      alpha[r] = __expf(m[r] - mn);
      m[r] = mn;
      const unsigned short p0 = f2b(__expf(s0[r] - mn));
      const unsigned short p1 = f2b(__expf(s1[r] - mn));
      plw[(hi * 4 + r) * 72 + lo] = p0;
      plw[(hi * 4 + r) * 72 + 16 + lo] = p1;
      float rs = b2f(p0) + b2f(p1);
      rs += __shfl_xor(rs, 1);
      rs += __shfl_xor(rs, 2);
      rs += __shfl_xor(rs, 4);
      rs += __shfl_xor(rs, 8);
      lsum[r] = lsum[r] * alpha[r] + rs;
    }
#pragma unroll
    for (int t2 = 0; t2 < 8; ++t2)
#pragma unroll
      for (int r = 0; r < 4; ++r) yacc[t2][r] *= alpha[r];
    // P (16x32) from LDS as MFMA A-frag (same-wave ds ordering, no barrier needed)
    const bf16x8 pf = *(const bf16x8*)&plw[lo * 72 + hi * 8];
#pragma unroll
    for (int t2 = 0; t2 < 8; ++t2) {
      const bf16x8 vf = *(const bf16x8*)&Vh[(long)(t2 * 16 + lo) * L_ + kv0 + hi * 8];
      yacc[t2] = __builtin_amdgcn_mfma_f32_16x16x32_bf16(pf, vf, yacc[t2], 0, 0, 0);
    }
  }
#pragma unroll
  for (int r = 0; r < 4; ++r) {
    const float inv = 1.0f / lsum[r];
    const long row = q0 + hi * 4 + r;
    unsigned short* yrow = Y + ((long)b * L_ + row) * D_ + h * DH;
#pragma unroll
    for (int t2 = 0; t2 < 8; ++t2)
      yrow[t2 * 16 + lo] = f2b(yacc[t2][r] * inv);
  }
}

extern "C" void kernel_launch(void* const* d_in, const int* in_sizes, int n_in,
                              void* d_out, int out_size, void* d_ws, size_t ws_size,
                              hipStream_t stream) {
  const float* x = (const float*)d_in[0];
  const float* wqkv = (const float*)d_in[1];
  const float* wo = (const float*)d_in[2];
  float* out = (float*)d_out;

  unsigned short* ws = (unsigned short*)d_ws;
  const size_t N_X = (size_t)B_ * L_ * D_;          // 8,388,608
  const size_t N_WQKV = (size_t)3 * D_ * D_;        // 12,582,912
  const size_t N_WO = (size_t)D_ * D_;              // 4,194,304
  const size_t N_QKV = (size_t)B_ * L_ * 3 * D_;    // 25,165,824
  const size_t N_HEAD = (size_t)B_ * H_ * L_ * DH;  // 8,388,608
  unsigned short* xb = ws;
  unsigned short* wqkb = xb + N_X;
  unsigned short* wob = wqkb + N_WQKV;
  unsigned short* qkv = wob + N_WO;
  unsigned short* Qb = qkv + N_QKV;
  unsigned short* Kb = Qb + N_HEAD;
  unsigned short* Vt = Kb + N_HEAD;
  unsigned short* Yb = Vt + N_HEAD;
  const size_t need = (size_t)(Yb + N_HEAD - ws) * sizeof(unsigned short);
  if (ws_size < need) return;  // insufficient scratch: fail visibly

  f32_to_bf16<<<2048, 256, 0, stream>>>(x, xb, (int)(N_X / 4));
  f32_to_bf16<<<2048, 256, 0, stream>>>(wqkv, wqkb, (int)(N_WQKV / 4));
  f32_to_bf16<<<2048, 256, 0, stream>>>(wo, wob, (int)(N_WO / 4));

  // qkv = x @ W_qkv^T  [4096 x 6144]
  gemm_bt<true><<<dim3(3 * D_ / 128, B_ * L_ / 128), 256, 0, stream>>>(
      xb, wqkb, qkv, B_ * L_, 3 * D_, D_);

  rope_qk<<<(B_ * H_ * L_ * 64) / 256, 256, 0, stream>>>(qkv, Qb, Kb);
  v_transpose<<<dim3(L_ / 64, B_ * H_), 256, 0, stream>>>(qkv, Vt);

  flash_attn<<<dim3(L_ / 64, H_, B_), 256, 0, stream>>>(Qb, Kb, Vt, Yb);

  // out = y @ W_o^T  [4096 x 2048] fp32
  gemm_bt<false><<<dim3(D_ / 128, B_ * L_ / 128), 256, 0, stream>>>(
      Yb, wob, out, B_ * L_, D_, D_);
}

// Round 2
// 379.721 us; speedup vs baseline: 2.0332x; 2.0332x over previous
//
#include <hip/hip_runtime.h>
#include <math.h>

typedef __bf16 bf16x8 __attribute__((ext_vector_type(8)));
typedef float f32x4 __attribute__((ext_vector_type(4)));
typedef unsigned short us8 __attribute__((ext_vector_type(8)));

#define B_ 2
#define L_ 2048
#define D_ 2048
#define H_ 16
#define DH 128

__device__ __forceinline__ unsigned short f2b(float f) {
  union { float f; unsigned u; } v; v.f = f;
  unsigned u = v.u;
  return (unsigned short)((u + 0x7fffu + ((u >> 16) & 1u)) >> 16);
}
__device__ __forceinline__ float b2f(unsigned short h) {
  union { unsigned u; float f; } v; v.u = ((unsigned)h) << 16;
  return v.f;
}

#define GLD16(g, l) __builtin_amdgcn_global_load_lds(                          \
    (const __attribute__((address_space(1))) void*)(g),                        \
    (__attribute__((address_space(3))) void*)(l), 16, 0, 0)

// ---------------- fp32 -> bf16 convert ----------------
__global__ void f32_to_bf16(const float* __restrict__ in,
                            unsigned short* __restrict__ out, int n4) {
  int i = blockIdx.x * blockDim.x + threadIdx.x;
  const int stride = gridDim.x * blockDim.x;
  for (; i < n4; i += stride) {
    const float4 v = ((const float4*)in)[i];
    ushort4 o;
    o.x = f2b(v.x); o.y = f2b(v.y); o.z = f2b(v.z); o.w = f2b(v.w);
    ((ushort4*)out)[i] = o;
  }
}

// ---------------- GEMM: C[m,n] = sum_k A[m,k]*B[n,k] ----------------
template <bool OUT_BF16>
__global__ __launch_bounds__(256)
void gemm_bt(const unsigned short* __restrict__ A,
             const unsigned short* __restrict__ Bm,
             void* __restrict__ Cv, int M, int N, int K) {
  __shared__ unsigned short lA[128 * 32];
  __shared__ unsigned short lB[128 * 32];
  const int tid = threadIdx.x;
  const int wave = tid >> 6, lane = tid & 63;
  const int lo = lane & 15, hi = lane >> 4;
  const int wm = (wave >> 1) * 64, wn = (wave & 1) * 64;
  const int bm = blockIdx.y, bn = blockIdx.x;
  f32x4 acc[4][4] = {};
  const long aBase = (long)bm * 128 * K;
  const long bBase = (long)bn * 128 * K;
  for (int k0 = 0; k0 < K; k0 += 32) {
    __syncthreads();
#pragma unroll
    for (int j = 0; j < 2; ++j) {
      const int c = j * 256 + tid;
      const int row = c >> 2, cq = c & 3;
      const int lbase = (j * 256 + wave * 64) * 8;
      GLD16(A + aBase + (long)row * K + k0 + cq * 8, &lA[lbase]);
      GLD16(Bm + bBase + (long)row * K + k0 + cq * 8, &lB[lbase]);
    }
    __syncthreads();
    bf16x8 af[4], bfr[4];
#pragma unroll
    for (int mi = 0; mi < 4; ++mi)
      af[mi] = *(const bf16x8*)&lA[(wm + mi * 16 + lo) * 32 + hi * 8];
#pragma unroll
    for (int ni = 0; ni < 4; ++ni)
      bfr[ni] = *(const bf16x8*)&lB[(wn + ni * 16 + lo) * 32 + hi * 8];
#pragma unroll
    for (int mi = 0; mi < 4; ++mi)
#pragma unroll
      for (int ni = 0; ni < 4; ++ni)
        acc[mi][ni] = __builtin_amdgcn_mfma_f32_16x16x32_bf16(
            af[mi], bfr[ni], acc[mi][ni], 0, 0, 0);
  }
  const int r0 = bm * 128 + wm, c0 = bn * 128 + wn;
#pragma unroll
  for (int mi = 0; mi < 4; ++mi) {
#pragma unroll
    for (int r = 0; r < 4; ++r) {
      const long row = r0 + mi * 16 + hi * 4 + r;
#pragma unroll
      for (int ni = 0; ni < 4; ++ni) {
        const int col = c0 + ni * 16 + lo;
        if (OUT_BF16)
          ((unsigned short*)Cv)[row * N + col] = f2b(acc[mi][ni][r]);
        else
          ((float*)Cv)[row * N + col] = acc[mi][ni][r];
      }
    }
  }
}

// ---------------- RoPE + scatter to [B,H,L,dh]; Q scaled by 1/sqrt(dh) ----------------
__global__ void rope_qk(const unsigned short* __restrict__ qkv,
                        unsigned short* __restrict__ Qo,
                        unsigned short* __restrict__ Ko) {
  const int idx = blockIdx.x * 256 + threadIdx.x;
  const int i = idx & 63;
  const int l = (idx >> 6) & (L_ - 1);
  const int h = (idx >> 17) & (H_ - 1);
  const int b = idx >> 21;
  const float invf = exp2f(-(float)i * 0.20762050593045077f);
  const float ang = (float)l * invf;
  float sn, cs;
  sincosf(ang, &sn, &cs);
  const long base = ((long)b * L_ + l) * (3 * D_) + h * DH + 2 * i;
  const unsigned qin = *(const unsigned*)&qkv[base];
  const unsigned kin = *(const unsigned*)&qkv[base + D_];
  const float q0 = b2f((unsigned short)qin), q1 = b2f((unsigned short)(qin >> 16));
  const float k0 = b2f((unsigned short)kin), k1 = b2f((unsigned short)(kin >> 16));
  const float sc = 0.08838834764831845f;
  const float qo0 = (q0 * cs - q1 * sn) * sc, qo1 = (q1 * cs + q0 * sn) * sc;
  const float ko0 = (k0 * cs - k1 * sn), ko1 = (k1 * cs + k0 * sn);
  const long oo = ((long)(b * H_ + h) * L_ + l) * DH + 2 * i;
  *(unsigned*)&Qo[oo] = (unsigned)f2b(qo0) | ((unsigned)f2b(qo1) << 16);
  *(unsigned*)&Ko[oo] = (unsigned)f2b(ko0) | ((unsigned)f2b(ko1) << 16);
}

// ---------------- V pack into MFMA B-fragment tiles ----------------
// Vf[((bh*64 + kv32)*8 + d16)*512 + lane*8 + e] = V[kv32*32 + (lane>>4)*8 + e][d16*16 + (lane&15)]
__global__ __launch_bounds__(256)
void v_fragpack(const unsigned short* __restrict__ qkv,
                unsigned short* __restrict__ Vf) {
  const int lblk = blockIdx.x;  // L/64
  const int bh = blockIdx.y;    // B*H
  const int b = bh >> 4, h = bh & 15;
  __shared__ unsigned short tile[64 * 137];
  const int tid = threadIdx.x;
  const int l0 = lblk * 64;
#pragma unroll
  for (int j = 0; j < 4; ++j) {
    const int c = j * 256 + tid;
    const int row = c >> 4, col8 = c & 15;
    const us8 v = *(const us8*)&qkv[((long)b * L_ + l0 + row) * (3 * D_) +
                                    2 * D_ + h * DH + col8 * 8];
    unsigned short* dst = &tile[row * 137 + col8 * 8];
#pragma unroll
    for (int e = 0; e < 8; ++e) dst[e] = v[e];
  }
  __syncthreads();
#pragma unroll
  for (int j = 0; j < 4; ++j) {
    const int c = j * 256 + tid;
    const int k32l = c >> 9, t2 = (c >> 6) & 7, lane = c & 63;
    const int lo = lane & 15, hi = lane >> 4;
    us8 v;
#pragma unroll
    for (int e = 0; e < 8; ++e)
      v[e] = tile[(k32l * 32 + hi * 8 + e) * 137 + t2 * 16 + lo];
    *(us8*)&Vf[(((size_t)bh * 64 + lblk * 2 + k32l) * 8 + t2) * 512 + lane * 8] = v;
  }
}

// ---------------- causal flash attention, swapped-QK^T, KVBLK=64 ----------------
__global__ __launch_bounds__(256)
void flash_attn2(const unsigned short* __restrict__ Q,
                 const unsigned short* __restrict__ Kg,
                 const unsigned short* __restrict__ Vf,
                 unsigned short* __restrict__ Y) {
  const int qb = (L_ / 64 - 1) - blockIdx.x;  // heavy blocks first
  const int h = blockIdx.y, b = blockIdx.z;
  const int tid = threadIdx.x;
  const int wave = tid >> 6, lane = tid & 63;
  const int lo = lane & 15, hi = lane >> 4;
  const int swz = (lo & 7) << 4;
  const int q0w = qb * 64 + wave * 16;
  const long hoff = ((long)(b * H_ + h)) * L_ * DH;
  const unsigned short* Qh = Q + hoff;
  const unsigned short* Kh = Kg + hoff;
  const unsigned short* Vfh = Vf + ((size_t)(b * H_ + h)) * (64 * 8 * 512);

  __shared__ unsigned short lK[2][64 * 128];
  __shared__ unsigned short pl[4][16 * 72];
  unsigned short* plw = &pl[wave][0];

  // K tile stage: LDS linear (required by global_load_lds), source pre-swizzled
  // so that LDS holds lK[row][col] at byte (row*256 + col*2) ^ ((row&7)<<4).
  auto stage = [&](int bufi, int kv0s) {
    unsigned short* bk = &lK[bufi][0];
#pragma unroll
    for (int j = 0; j < 4; ++j) {
      const int c = j * 256 + tid;
      const int row = c >> 4;
      const int soff = ((c & 15) ^ (row & 7)) << 3;  // halves within row
      GLD16(Kh + (long)(kv0s + row) * DH + soff, &bk[(c & ~63) * 8]);
    }
  };

  bf16x8 qf[4];
#pragma unroll
  for (int s = 0; s < 4; ++s)
    qf[s] = *(const bf16x8*)&Qh[(long)(q0w + lo) * DH + s * 32 + hi * 8];

  float m = -INFINITY, lsum = 0.f;
  f32x4 yacc[8] = {};

  const int nIter = qb + 1;
  stage(0, 0);
  __syncthreads();

  for (int it = 0; it < nIter; ++it) {
    const int kv0 = it * 64;
    const bool active = (kv0 <= q0w + 15);
    const unsigned short* vbase = Vfh + (size_t)(it * 16) * 512 + lane * 8;
    bf16x8 vf0[8];
    if (active) {
#pragma unroll
      for (int t2 = 0; t2 < 8; ++t2)
        vf0[t2] = *(const bf16x8*)(vbase + t2 * 512);
    }
    if (it + 1 < nIter) stage((it + 1) & 1, kv0 + 64);
    if (active) {
      const char* bkc = (const char*)&lK[it & 1][0];
      // S^T = K * Q^T : lane holds S[q = q0w+lo][kv = kv0 + t*16 + hi*4 + r]
      f32x4 st[4] = {};
#pragma unroll
      for (int s = 0; s < 4; ++s) {
        const int inner = (lo * 256 + s * 64 + hi * 16) ^ swz;
#pragma unroll
        for (int t = 0; t < 4; ++t) {
          const bf16x8 kf = *(const bf16x8*)(bkc + t * 4096 + inner);
          st[t] = __builtin_amdgcn_mfma_f32_16x16x32_bf16(kf, qf[s], st[t], 0, 0, 0);
        }
      }
      bf16x8 vf1[8];
#pragma unroll
      for (int t2 = 0; t2 < 8; ++t2)
        vf1[t2] = *(const bf16x8*)(vbase + (8 + t2) * 512);
      if (kv0 + 63 > q0w) {
#pragma unroll
        for (int t = 0; t < 4; ++t)
#pragma unroll
          for (int r = 0; r < 4; ++r)
            if (kv0 + t * 16 + hi * 4 + r > q0w + lo) st[t][r] = -INFINITY;
      }
      // in-lane max over 16, then cross-hi (2 shfl)
      float tm[4];
#pragma unroll
      for (int t = 0; t < 4; ++t)
        tm[t] = fmaxf(fmaxf(st[t][0], st[t][1]), fmaxf(st[t][2], st[t][3]));
      float rm = fmaxf(fmaxf(tm[0], tm[1]), fmaxf(tm[2], tm[3]));
      rm = fmaxf(rm, __shfl_xor(rm, 16));
      rm = fmaxf(rm, __shfl_xor(rm, 32));
      const float mn = fmaxf(m, rm);
      const float alpha = __expf(m - mn);
      m = mn;
      float rs = 0.f;
#pragma unroll
      for (int t = 0; t < 4; ++t) {
#pragma unroll
        for (int r2 = 0; r2 < 2; ++r2) {
          const unsigned short p0 = f2b(__expf(st[t][2 * r2] - mn));
          const unsigned short p1 = f2b(__expf(st[t][2 * r2 + 1] - mn));
          *(unsigned*)&plw[lo * 72 + t * 16 + hi * 4 + 2 * r2] =
              (unsigned)p0 | ((unsigned)p1 << 16);
          rs += b2f(p0) + b2f(p1);
        }
      }
      rs += __shfl_xor(rs, 16);
      rs += __shfl_xor(rs, 32);
      lsum = lsum * alpha + rs;
      // redistribute alpha to output-row lanes (q_local = hi*4+r)
      float ar[4];
#pragma unroll
      for (int r = 0; r < 4; ++r) ar[r] = __shfl(alpha, hi * 4 + r);
#pragma unroll
      for (int t2 = 0; t2 < 8; ++t2)
#pragma unroll
        for (int r = 0; r < 4; ++r) yacc[t2][r] *= ar[r];
      // PV: y += P[q][kv] * V[kv][d]
#pragma unroll
      for (int kt = 0; kt < 2; ++kt) {
        const bf16x8 pf = *(const bf16x8*)&plw[lo * 72 + kt * 32 + hi * 8];
#pragma unroll
        for (int t2 = 0; t2 < 8; ++t2)
          yacc[t2] = __builtin_amdgcn_mfma_f32_16x16x32_bf16(
              pf, kt ? vf1[t2] : vf0[t2], yacc[t2], 0, 0, 0);
      }
    }
    __syncthreads();
  }
  const float inv = 1.f / lsum;
  float ir[4];
#pragma unroll
  for (int r = 0; r < 4; ++r) ir[r] = __shfl(inv, hi * 4 + r);
#pragma unroll
  for (int r = 0; r < 4; ++r) {
    const long row = q0w + hi * 4 + r;
    unsigned short* yrow = Y + ((long)b * L_ + row) * D_ + h * DH;
#pragma unroll
    for (int t2 = 0; t2 < 8; ++t2)
      yrow[t2 * 16 + lo] = f2b(yacc[t2][r] * ir[r]);
  }
}

extern "C" void kernel_launch(void* const* d_in, const int* in_sizes, int n_in,
                              void* d_out, int out_size, void* d_ws, size_t ws_size,
                              hipStream_t stream) {
  const float* x = (const float*)d_in[0];
  const float* wqkv = (const float*)d_in[1];
  const float* wo = (const float*)d_in[2];
  float* out = (float*)d_out;

  unsigned short* ws = (unsigned short*)d_ws;
  const size_t N_X = (size_t)B_ * L_ * D_;
  const size_t N_WQKV = (size_t)3 * D_ * D_;
  const size_t N_WO = (size_t)D_ * D_;
  const size_t N_QKV = (size_t)B_ * L_ * 3 * D_;
  const size_t N_HEAD = (size_t)B_ * H_ * L_ * DH;
  unsigned short* xb = ws;
  unsigned short* wqkb = xb + N_X;
  unsigned short* wob = wqkb + N_WQKV;
  unsigned short* qkv = wob + N_WO;
  unsigned short* Qb = qkv + N_QKV;
  unsigned short* Kb = Qb + N_HEAD;
  unsigned short* Vf = Kb + N_HEAD;
  unsigned short* Yb = Vf + N_HEAD;
  const size_t need = (size_t)(Yb + N_HEAD - ws) * sizeof(unsigned short);
  if (ws_size < need) return;

  f32_to_bf16<<<2048, 256, 0, stream>>>(x, xb, (int)(N_X / 4));
  f32_to_bf16<<<2048, 256, 0, stream>>>(wqkv, wqkb, (int)(N_WQKV / 4));
  f32_to_bf16<<<2048, 256, 0, stream>>>(wo, wob, (int)(N_WO / 4));

  gemm_bt<true><<<dim3(3 * D_ / 128, B_ * L_ / 128), 256, 0, stream>>>(
      xb, wqkb, qkv, B_ * L_, 3 * D_, D_);

  rope_qk<<<(B_ * H_ * L_ * 64) / 256, 256, 0, stream>>>(qkv, Qb, Kb);
  v_fragpack<<<dim3(L_ / 64, B_ * H_), 256, 0, stream>>>(qkv, Vf);

  flash_attn2<<<dim3(L_ / 64, H_, B_), 256, 0, stream>>>(Qb, Kb, Vf, Yb);

  gemm_bt<false><<<dim3(D_ / 128, B_ * L_ / 128), 256, 0, stream>>>(
      Yb, wob, out, B_ * L_, D_, D_);
}

// Round 3
// 323.740 us; speedup vs baseline: 2.3847x; 1.1729x over previous
//
#include <hip/hip_runtime.h>
#include <math.h>

typedef __bf16 bf16x8 __attribute__((ext_vector_type(8)));
typedef float f32x4 __attribute__((ext_vector_type(4)));
typedef unsigned short us8 __attribute__((ext_vector_type(8)));

#define B_ 2
#define L_ 2048
#define D_ 2048
#define H_ 16
#define DH 128

__device__ __forceinline__ unsigned short f2b(float f) {
  union { float f; unsigned u; } v; v.f = f;
  unsigned u = v.u;
  return (unsigned short)((u + 0x7fffu + ((u >> 16) & 1u)) >> 16);
}
__device__ __forceinline__ float b2f(unsigned short h) {
  union { unsigned u; float f; } v; v.u = ((unsigned)h) << 16;
  return v.f;
}

#define GLD16(g, l) __builtin_amdgcn_global_load_lds(                          \
    (const __attribute__((address_space(1))) void*)(g),                        \
    (__attribute__((address_space(3))) void*)(l), 16, 0, 0)

// ---------------- fp32 -> bf16 convert ----------------
__global__ void f32_to_bf16(const float* __restrict__ in,
                            unsigned short* __restrict__ out, int n4) {
  int i = blockIdx.x * blockDim.x + threadIdx.x;
  const int stride = gridDim.x * blockDim.x;
  for (; i < n4; i += stride) {
    const float4 v = ((const float4*)in)[i];
    ushort4 o;
    o.x = f2b(v.x); o.y = f2b(v.y); o.z = f2b(v.z); o.w = f2b(v.w);
    ((ushort4*)out)[i] = o;
  }
}

// ---------------- GEMM: C[m,n] = sum_k A[m,k]*B[n,k] ----------------
template <bool OUT_BF16>
__global__ __launch_bounds__(256)
void gemm_bt(const unsigned short* __restrict__ A,
             const unsigned short* __restrict__ Bm,
             void* __restrict__ Cv, int M, int N, int K) {
  __shared__ unsigned short lA[128 * 32];
  __shared__ unsigned short lB[128 * 32];
  const int tid = threadIdx.x;
  const int wave = tid >> 6, lane = tid & 63;
  const int lo = lane & 15, hi = lane >> 4;
  const int wm = (wave >> 1) * 64, wn = (wave & 1) * 64;
  const int bm = blockIdx.y, bn = blockIdx.x;
  f32x4 acc[4][4] = {};
  const long aBase = (long)bm * 128 * K;
  const long bBase = (long)bn * 128 * K;
  for (int k0 = 0; k0 < K; k0 += 32) {
    __syncthreads();
#pragma unroll
    for (int j = 0; j < 2; ++j) {
      const int c = j * 256 + tid;
      const int row = c >> 2, cq = c & 3;
      const int lbase = (j * 256 + wave * 64) * 8;
      GLD16(A + aBase + (long)row * K + k0 + cq * 8, &lA[lbase]);
      GLD16(Bm + bBase + (long)row * K + k0 + cq * 8, &lB[lbase]);
    }
    __syncthreads();
    bf16x8 af[4], bfr[4];
#pragma unroll
    for (int mi = 0; mi < 4; ++mi)
      af[mi] = *(const bf16x8*)&lA[(wm + mi * 16 + lo) * 32 + hi * 8];
#pragma unroll
    for (int ni = 0; ni < 4; ++ni)
      bfr[ni] = *(const bf16x8*)&lB[(wn + ni * 16 + lo) * 32 + hi * 8];
#pragma unroll
    for (int mi = 0; mi < 4; ++mi)
#pragma unroll
      for (int ni = 0; ni < 4; ++ni)
        acc[mi][ni] = __builtin_amdgcn_mfma_f32_16x16x32_bf16(
            af[mi], bfr[ni], acc[mi][ni], 0, 0, 0);
  }
  const int r0 = bm * 128 + wm, c0 = bn * 128 + wn;
#pragma unroll
  for (int mi = 0; mi < 4; ++mi) {
#pragma unroll
    for (int r = 0; r < 4; ++r) {
      const long row = r0 + mi * 16 + hi * 4 + r;
#pragma unroll
      for (int ni = 0; ni < 4; ++ni) {
        const int col = c0 + ni * 16 + lo;
        if (OUT_BF16)
          ((unsigned short*)Cv)[row * N + col] = f2b(acc[mi][ni][r]);
        else
          ((float*)Cv)[row * N + col] = acc[mi][ni][r];
      }
    }
  }
}

// ---------------- RoPE + scatter to [B,H,L,dh]; Q scaled by log2(e)/sqrt(dh) ----------------
__global__ void rope_qk(const unsigned short* __restrict__ qkv,
                        unsigned short* __restrict__ Qo,
                        unsigned short* __restrict__ Ko) {
  const int idx = blockIdx.x * 256 + threadIdx.x;
  const int i = idx & 63;
  const int l = (idx >> 6) & (L_ - 1);
  const int h = (idx >> 17) & (H_ - 1);
  const int b = idx >> 21;
  const float invf = exp2f(-(float)i * 0.20762050593045077f);
  const float ang = (float)l * invf;
  float sn, cs;
  sincosf(ang, &sn, &cs);
  const long base = ((long)b * L_ + l) * (3 * D_) + h * DH + 2 * i;
  const unsigned qin = *(const unsigned*)&qkv[base];
  const unsigned kin = *(const unsigned*)&qkv[base + D_];
  const float q0 = b2f((unsigned short)qin), q1 = b2f((unsigned short)(qin >> 16));
  const float k0 = b2f((unsigned short)kin), k1 = b2f((unsigned short)(kin >> 16));
  const float sc = 0.12751743f;  // log2(e)/sqrt(128): softmax in exp2 domain
  const float qo0 = (q0 * cs - q1 * sn) * sc, qo1 = (q1 * cs + q0 * sn) * sc;
  const float ko0 = (k0 * cs - k1 * sn), ko1 = (k1 * cs + k0 * sn);
  const long oo = ((long)(b * H_ + h) * L_ + l) * DH + 2 * i;
  *(unsigned*)&Qo[oo] = (unsigned)f2b(qo0) | ((unsigned)f2b(qo1) << 16);
  *(unsigned*)&Ko[oo] = (unsigned)f2b(ko0) | ((unsigned)f2b(ko1) << 16);
}

// ---------------- V pack into MFMA B-fragment tiles ----------------
__global__ __launch_bounds__(256)
void v_fragpack(const unsigned short* __restrict__ qkv,
                unsigned short* __restrict__ Vf) {
  const int lblk = blockIdx.x;  // L/64
  const int bh = blockIdx.y;    // B*H
  const int b = bh >> 4, h = bh & 15;
  __shared__ unsigned short tile[64 * 137];
  const int tid = threadIdx.x;
  const int l0 = lblk * 64;
#pragma unroll
  for (int j = 0; j < 4; ++j) {
    const int c = j * 256 + tid;
    const int row = c >> 4, col8 = c & 15;
    const us8 v = *(const us8*)&qkv[((long)b * L_ + l0 + row) * (3 * D_) +
                                    2 * D_ + h * DH + col8 * 8];
    unsigned short* dst = &tile[row * 137 + col8 * 8];
#pragma unroll
    for (int e = 0; e < 8; ++e) dst[e] = v[e];
  }
  __syncthreads();
#pragma unroll
  for (int j = 0; j < 4; ++j) {
    const int c = j * 256 + tid;
    const int k32l = c >> 9, t2 = (c >> 6) & 7, lane = c & 63;
    const int lo = lane & 15, hi = lane >> 4;
    us8 v;
#pragma unroll
    for (int e = 0; e < 8; ++e)
      v[e] = tile[(k32l * 32 + hi * 8 + e) * 137 + t2 * 16 + lo];
    *(us8*)&Vf[(((size_t)bh * 64 + lblk * 2 + k32l) * 8 + t2) * 512 + lane * 8] = v;
  }
}

// ---------------- causal flash attention: fold-paired q-tiles, swapped QK^T ----------------
// Block p owns q-tiles tA=p (light) and tB=31-p (heavy): uniform 33 MFMA-iters/block.
__global__ __launch_bounds__(256, 2)
void flash_attn3(const unsigned short* __restrict__ Q,
                 const unsigned short* __restrict__ Kg,
                 const unsigned short* __restrict__ Vf,
                 unsigned short* __restrict__ Y) {
  const int p = blockIdx.x;  // 0..15, heavy pairs dispatched first
  const int tA = p, tB = (L_ / 64 - 1) - p;
  const int h = blockIdx.y, b = blockIdx.z;
  const int tid = threadIdx.x;
  const int wave = tid >> 6, lane = tid & 63;
  const int lo = lane & 15, hi = lane >> 4;
  const int swz = (lo & 7) << 4;
  const int qA = tA * 64 + wave * 16;
  const int qB = tB * 64 + wave * 16;
  const long hoff = ((long)(b * H_ + h)) * L_ * DH;
  const unsigned short* Qh = Q + hoff;
  const unsigned short* Kh = Kg + hoff;
  const unsigned short* Vfh = Vf + ((size_t)(b * H_ + h)) * (64 * 8 * 512);

  __shared__ unsigned short lK[2][64 * 128];
  __shared__ unsigned short pl[4][2][16 * 72];
  unsigned short* plA = &pl[wave][0][0];
  unsigned short* plB = &pl[wave][1][0];

  auto stage = [&](int bufi, int kv0s) {
    unsigned short* bk = &lK[bufi][0];
#pragma unroll
    for (int j = 0; j < 4; ++j) {
      const int c = j * 256 + tid;
      const int row = c >> 4;
      const int soff = ((c & 15) ^ (row & 7)) << 3;
      GLD16(Kh + (long)(kv0s + row) * DH + soff, &bk[(c & ~63) * 8]);
    }
  };

  bf16x8 qfA[4], qfB[4];
#pragma unroll
  for (int s = 0; s < 4; ++s) {
    qfA[s] = *(const bf16x8*)&Qh[(long)(qA + lo) * DH + s * 32 + hi * 8];
    qfB[s] = *(const bf16x8*)&Qh[(long)(qB + lo) * DH + s * 32 + hi * 8];
  }

  float mA = -INFINITY, lsA = 0.f, mB = -INFINITY, lsB = 0.f;
  f32x4 yA[8] = {}, yB[8] = {};

  // exp2-domain online softmax with defer-max (THR=8)
  auto softmax = [&](f32x4 (&st)[4], float& m, float& lsum, f32x4 (&yacc)[8],
                     unsigned short* plw, int qw, int kv0) {
    if (kv0 + 63 > qw) {  // diagonal: causal mask
      const int d0 = qw + lo - kv0 - hi * 4;
#pragma unroll
      for (int t = 0; t < 4; ++t) {
        const int dt = d0 - t * 16;
#pragma unroll
        for (int r = 0; r < 4; ++r)
          if (r > dt) st[t][r] = -INFINITY;
      }
    }
    float tm0 = fmaxf(fmaxf(st[0][0], st[0][1]), fmaxf(st[0][2], st[0][3]));
    float tm1 = fmaxf(fmaxf(st[1][0], st[1][1]), fmaxf(st[1][2], st[1][3]));
    float tm2 = fmaxf(fmaxf(st[2][0], st[2][1]), fmaxf(st[2][2], st[2][3]));
    float tm3 = fmaxf(fmaxf(st[3][0], st[3][1]), fmaxf(st[3][2], st[3][3]));
    float rm = fmaxf(fmaxf(tm0, tm1), fmaxf(tm2, tm3));
    rm = fmaxf(rm, __shfl_xor(rm, 16));
    rm = fmaxf(rm, __shfl_xor(rm, 32));
    if (!__all(rm <= m + 8.f)) {  // rescale path (rare after warmup)
      const float mn = fmaxf(m, rm);
      const float alpha = exp2f(m - mn);
      m = mn;
      lsum *= alpha;
      float ar[4];
#pragma unroll
      for (int r = 0; r < 4; ++r) ar[r] = __shfl(alpha, hi * 4 + r);
#pragma unroll
      for (int t2 = 0; t2 < 8; ++t2)
#pragma unroll
        for (int r = 0; r < 4; ++r) yacc[t2][r] *= ar[r];
    }
    float rs = 0.f;
#pragma unroll
    for (int t = 0; t < 4; ++t) {
#pragma unroll
      for (int r2 = 0; r2 < 2; ++r2) {
        const float e0 = exp2f(st[t][2 * r2] - m);
        const float e1 = exp2f(st[t][2 * r2 + 1] - m);
        rs += e0 + e1;
        const unsigned short u0 = __builtin_bit_cast(unsigned short, (__bf16)e0);
        const unsigned short u1 = __builtin_bit_cast(unsigned short, (__bf16)e1);
        *(unsigned*)&plw[lo * 72 + t * 16 + hi * 4 + 2 * r2] =
            (unsigned)u0 | ((unsigned)u1 << 16);
      }
    }
    rs += __shfl_xor(rs, 16);
    rs += __shfl_xor(rs, 32);
    lsum += rs;
  };

  const int nIter = tB + 1;
  stage(0, 0);
  __syncthreads();

  for (int it = 0; it < nIter; ++it) {
    const int kv0 = it * 64;
    const bool aAct = (it <= tA);
    if (it + 1 < nIter) stage((it + 1) & 1, kv0 + 64);
    const char* bkc = (const char*)&lK[it & 1][0];
    f32x4 stA[4] = {}, stB[4] = {};
    if (aAct) {
#pragma unroll
      for (int s = 0; s < 4; ++s) {
        const int inner = (lo * 256 + s * 64 + hi * 16) ^ swz;
#pragma unroll
        for (int t = 0; t < 4; ++t) {
          const bf16x8 kf = *(const bf16x8*)(bkc + t * 4096 + inner);
          stA[t] = __builtin_amdgcn_mfma_f32_16x16x32_bf16(kf, qfA[s], stA[t], 0, 0, 0);
          stB[t] = __builtin_amdgcn_mfma_f32_16x16x32_bf16(kf, qfB[s], stB[t], 0, 0, 0);
        }
      }
    } else {
#pragma unroll
      for (int s = 0; s < 4; ++s) {
        const int inner = (lo * 256 + s * 64 + hi * 16) ^ swz;
#pragma unroll
        for (int t = 0; t < 4; ++t) {
          const bf16x8 kf = *(const bf16x8*)(bkc + t * 4096 + inner);
          stB[t] = __builtin_amdgcn_mfma_f32_16x16x32_bf16(kf, qfB[s], stB[t], 0, 0, 0);
        }
      }
    }
    if (aAct) softmax(stA, mA, lsA, yA, plA, qA, kv0);
    softmax(stB, mB, lsB, yB, plB, qB, kv0);
    const unsigned short* vbase = Vfh + (size_t)(it * 16) * 512 + lane * 8;
#pragma unroll
    for (int kt = 0; kt < 2; ++kt) {
      bf16x8 vf[8];
#pragma unroll
      for (int t2 = 0; t2 < 8; ++t2)
        vf[t2] = *(const bf16x8*)(vbase + (size_t)(kt * 8 + t2) * 512);
      const bf16x8 pfB = *(const bf16x8*)&plB[lo * 72 + kt * 32 + hi * 8];
#pragma unroll
      for (int t2 = 0; t2 < 8; ++t2)
        yB[t2] = __builtin_amdgcn_mfma_f32_16x16x32_bf16(pfB, vf[t2], yB[t2], 0, 0, 0);
      if (aAct) {
        const bf16x8 pfA = *(const bf16x8*)&plA[lo * 72 + kt * 32 + hi * 8];
#pragma unroll
        for (int t2 = 0; t2 < 8; ++t2)
          yA[t2] = __builtin_amdgcn_mfma_f32_16x16x32_bf16(pfA, vf[t2], yA[t2], 0, 0, 0);
      }
    }
    __syncthreads();
  }

  auto wout = [&](f32x4 (&yacc)[8], float lsum, int qw) {
    const float inv = 1.f / lsum;
    float ir[4];
#pragma unroll
    for (int r = 0; r < 4; ++r) ir[r] = __shfl(inv, hi * 4 + r);
#pragma unroll
    for (int r = 0; r < 4; ++r) {
      const long row = qw + hi * 4 + r;
      unsigned short* yrow = Y + ((long)b * L_ + row) * D_ + h * DH;
#pragma unroll
      for (int t2 = 0; t2 < 8; ++t2)
        yrow[t2 * 16 + lo] = f2b(yacc[t2][r] * ir[r]);
    }
  };
  wout(yA, lsA, qA);
  wout(yB, lsB, qB);
}

extern "C" void kernel_launch(void* const* d_in, const int* in_sizes, int n_in,
                              void* d_out, int out_size, void* d_ws, size_t ws_size,
                              hipStream_t stream) {
  const float* x = (const float*)d_in[0];
  const float* wqkv = (const float*)d_in[1];
  const float* wo = (const float*)d_in[2];
  float* out = (float*)d_out;

  unsigned short* ws = (unsigned short*)d_ws;
  const size_t N_X = (size_t)B_ * L_ * D_;
  const size_t N_WQKV = (size_t)3 * D_ * D_;
  const size_t N_WO = (size_t)D_ * D_;
  const size_t N_QKV = (size_t)B_ * L_ * 3 * D_;
  const size_t N_HEAD = (size_t)B_ * H_ * L_ * DH;
  unsigned short* xb = ws;
  unsigned short* wqkb = xb + N_X;
  unsigned short* wob = wqkb + N_WQKV;
  unsigned short* qkv = wob + N_WO;
  unsigned short* Qb = qkv + N_QKV;
  unsigned short* Kb = Qb + N_HEAD;
  unsigned short* Vf = Kb + N_HEAD;
  unsigned short* Yb = Vf + N_HEAD;
  const size_t need = (size_t)(Yb + N_HEAD - ws) * sizeof(unsigned short);
  if (ws_size < need) return;

  f32_to_bf16<<<2048, 256, 0, stream>>>(x, xb, (int)(N_X / 4));
  f32_to_bf16<<<2048, 256, 0, stream>>>(wqkv, wqkb, (int)(N_WQKV / 4));
  f32_to_bf16<<<2048, 256, 0, stream>>>(wo, wob, (int)(N_WO / 4));

  gemm_bt<true><<<dim3(3 * D_ / 128, B_ * L_ / 128), 256, 0, stream>>>(
      xb, wqkb, qkv, B_ * L_, 3 * D_, D_);

  rope_qk<<<(B_ * H_ * L_ * 64) / 256, 256, 0, stream>>>(qkv, Qb, Kb);
  v_fragpack<<<dim3(L_ / 64, B_ * H_), 256, 0, stream>>>(qkv, Vf);

  flash_attn3<<<dim3(16, H_, B_), 256, 0, stream>>>(Qb, Kb, Vf, Yb);

  gemm_bt<false><<<dim3(D_ / 128, B_ * L_ / 128), 256, 0, stream>>>(
      Yb, wob, out, B_ * L_, D_, D_);
}

// Round 4
// 296.406 us; speedup vs baseline: 2.6046x; 1.0922x over previous
//
#include <hip/hip_runtime.h>
#include <math.h>

typedef __bf16 bf16x8 __attribute__((ext_vector_type(8)));
typedef float f32x4 __attribute__((ext_vector_type(4)));
typedef unsigned short us8 __attribute__((ext_vector_type(8)));

#define B_ 2
#define L_ 2048
#define D_ 2048
#define H_ 16
#define DH 128

__device__ __forceinline__ unsigned short f2b(float f) {
  union { float f; unsigned u; } v; v.f = f;
  unsigned u = v.u;
  return (unsigned short)((u + 0x7fffu + ((u >> 16) & 1u)) >> 16);
}
__device__ __forceinline__ float b2f(unsigned short h) {
  union { unsigned u; float f; } v; v.u = ((unsigned)h) << 16;
  return v.f;
}

#define GLD16(g, l) __builtin_amdgcn_global_load_lds(                          \
    (const __attribute__((address_space(1))) void*)(g),                        \
    (__attribute__((address_space(3))) void*)(l), 16, 0, 0)

// ---------------- fp32 -> bf16 convert ----------------
__global__ void f32_to_bf16(const float* __restrict__ in,
                            unsigned short* __restrict__ out, int n4) {
  int i = blockIdx.x * blockDim.x + threadIdx.x;
  const int stride = gridDim.x * blockDim.x;
  for (; i < n4; i += stride) {
    const float4 v = ((const float4*)in)[i];
    ushort4 o;
    o.x = f2b(v.x); o.y = f2b(v.y); o.z = f2b(v.z); o.w = f2b(v.w);
    ((ushort4*)out)[i] = o;
  }
}

// ---------------- 8-phase 256x256x64 GEMM: C[m,n] = sum_k A[m,k]*B[n,k] ----------------
// 8 waves (2M x 4N), dbuf LDS 128 KB, counted vmcnt(2) at phases 4/8 only,
// T2 slot^row&7 swizzle, T5 setprio, T1 XCD swizzle. Requires K%128==0,
// M%256==0, N%256==0, grid=(M/256)*(N/256) with nwg%8==0.

#define SB()                              \
  do {                                    \
    __builtin_amdgcn_s_barrier();         \
    __builtin_amdgcn_sched_barrier(0);    \
  } while (0)

#define VMC2() asm volatile("s_waitcnt vmcnt(2)" ::: "memory")

#define LOAD_A(BUF, MH)                                                        \
  _Pragma("unroll") for (int q = 0; q < 4; ++q) {                              \
    const int rowA = (MH) * 64 + q * 16 + lo;                                  \
    _Pragma("unroll") for (int kk = 0; kk < 2; ++kk)                           \
        af[q][kk] = *(const bf16x8*)&lds[0][BUF][wmh]                          \
            [rowA * 64 + ((kk * 4 + hi) ^ sw) * 8];                            \
  }

#define LOAD_B(BUF, NH)                                                        \
  _Pragma("unroll") for (int j = 0; j < 2; ++j) {                              \
    const int rowB = bro + ((NH) * 2 + j) * 16;                                \
    _Pragma("unroll") for (int kk = 0; kk < 2; ++kk)                           \
        bfr[j][kk] = *(const bf16x8*)&lds[1][BUF][bhalf]                       \
            [rowB * 64 + ((kk * 4 + hi) ^ sw) * 8];                            \
  }

#define MFMA16(MH, NH)                                                         \
  do {                                                                         \
    __builtin_amdgcn_s_setprio(1);                                             \
    _Pragma("unroll") for (int q = 0; q < 4; ++q) {                            \
      _Pragma("unroll") for (int j = 0; j < 2; ++j) {                          \
        acc[(MH) * 4 + q][(NH) * 2 + j] =                                      \
            __builtin_amdgcn_mfma_f32_16x16x32_bf16(                           \
                af[q][0], bfr[j][0], acc[(MH) * 4 + q][(NH) * 2 + j], 0, 0, 0);\
        acc[(MH) * 4 + q][(NH) * 2 + j] =                                      \
            __builtin_amdgcn_mfma_f32_16x16x32_bf16(                           \
                af[q][1], bfr[j][1], acc[(MH) * 4 + q][(NH) * 2 + j], 0, 0, 0);\
      }                                                                        \
    }                                                                          \
    __builtin_amdgcn_s_setprio(0);                                             \
  } while (0)

template <bool OUT_BF16>
__global__ __launch_bounds__(512)
void gemm8p(const unsigned short* __restrict__ A,
            const unsigned short* __restrict__ Bm,
            void* __restrict__ Cv, int M, int N, int K) {
  __shared__ __align__(16) unsigned short lds[2][2][2][128 * 64];
  const int tid = threadIdx.x;
  const int w = tid >> 6, lane = tid & 63;
  const int lo = lane & 15, hi = lane >> 4, sw = lo & 7;
  const int wmh = w >> 2;        // this wave's A half (rows wmh*128..+127)
  const int wn = (w & 3) * 64;   // this wave's 64-col C window
  const int bhalf = wn >> 7, bro = (wn & 64) + lo;
  const int GM = M >> 8;
  const int nwg = gridDim.x;
  const int f = blockIdx.x;
  const int v = (f & 7) * (nwg >> 3) + (f >> 3);  // bijective XCD swizzle
  const int bn = v / GM, bm = v % GM;             // bn-major chunks per XCD
  const int NI = K >> 7;

  auto stageU = [&](int mat, int buf, int half, int tile) {
    const unsigned short* G = mat ? Bm : A;
    const int r256 = (mat ? bn : bm) * 256 + half * 128;
#pragma unroll
    for (int u = 0; u < 2; ++u) {
      const int c = u * 512 + tid;
      const int row = c >> 3;
      const int gs = (c & 7) ^ (row & 7);  // pre-swizzled source slot
      GLD16(G + (long)(r256 + row) * K + tile * 64 + gs * 8,
            &lds[mat][buf][half][(u * 512 + (tid & ~63)) * 8]);
    }
  };

  f32x4 acc[8][4] = {};
  bf16x8 af[4][2], bfr[2][2];

  // prologue: tile0 full -> buf0, tile1.A0 -> buf1
  stageU(0, 0, 0, 0); stageU(0, 0, 1, 0);
  stageU(1, 0, 0, 0); stageU(1, 0, 1, 0);
  stageU(0, 1, 0, 1);
  VMC2();
  SB();

  for (int i = 0; i < NI; ++i) {
    const int t1 = 2 * i + 1;
    const bool nx = (i + 1 < NI);
    // p1: tile 2i (buf0) quad (0,0); stage T(2i+1).B0
    LOAD_A(0, 0) LOAD_B(0, 0)
    stageU(1, 1, 0, t1);
    SB(); MFMA16(0, 0); SB();
    // p2: quad (0,1); stage T(2i+1).A1
    LOAD_B(0, 1)
    stageU(0, 1, 1, t1);
    SB(); MFMA16(0, 1); SB();
    // p3: quad (1,1); stage T(2i+1).B1
    LOAD_A(0, 1)
    stageU(1, 1, 1, t1);
    SB(); MFMA16(1, 1); SB();
    // p4: quad (1,0); stage T(2i+2).A0; counted vmcnt
    LOAD_B(0, 0)
    if (nx) stageU(0, 0, 0, t1 + 1);
    SB(); MFMA16(1, 0);
    VMC2();
    SB();
    // p5: tile 2i+1 (buf1) quad (0,0); stage T(2i+2).A1
    LOAD_A(1, 0) LOAD_B(1, 0)
    if (nx) stageU(0, 0, 1, t1 + 1);
    SB(); MFMA16(0, 0); SB();
    // p6: quad (0,1); stage T(2i+2).B0
    LOAD_B(1, 1)
    if (nx) stageU(1, 0, 0, t1 + 1);
    SB(); MFMA16(0, 1); SB();
    // p7: quad (1,1); stage T(2i+2).B1
    LOAD_A(1, 1)
    if (nx) stageU(1, 0, 1, t1 + 1);
    SB(); MFMA16(1, 1); SB();
    // p8: quad (1,0); stage T(2i+3).A0; counted vmcnt
    LOAD_B(1, 0)
    if (nx) stageU(0, 1, 0, t1 + 2);
    SB(); MFMA16(1, 0);
    VMC2();
    SB();
  }

  const int r0 = bm * 256 + wmh * 128;
  const int c0 = bn * 256 + wn;
#pragma unroll
  for (int mi = 0; mi < 8; ++mi) {
#pragma unroll
    for (int r = 0; r < 4; ++r) {
      const long row = r0 + mi * 16 + hi * 4 + r;
#pragma unroll
      for (int ni = 0; ni < 4; ++ni) {
        const int col = c0 + ni * 16 + lo;
        if (OUT_BF16)
          ((unsigned short*)Cv)[row * N + col] = f2b(acc[mi][ni][r]);
        else
          ((float*)Cv)[row * N + col] = acc[mi][ni][r];
      }
    }
  }
}

// ---------------- RoPE + scatter to [B,H,L,dh]; Q scaled by log2(e)/sqrt(dh) ----------------
__global__ void rope_qk(const unsigned short* __restrict__ qkv,
                        unsigned short* __restrict__ Qo,
                        unsigned short* __restrict__ Ko) {
  const int idx = blockIdx.x * 256 + threadIdx.x;
  const int i = idx & 63;
  const int l = (idx >> 6) & (L_ - 1);
  const int h = (idx >> 17) & (H_ - 1);
  const int b = idx >> 21;
  const float invf = exp2f(-(float)i * 0.20762050593045077f);
  const float ang = (float)l * invf;
  float sn, cs;
  sincosf(ang, &sn, &cs);
  const long base = ((long)b * L_ + l) * (3 * D_) + h * DH + 2 * i;
  const unsigned qin = *(const unsigned*)&qkv[base];
  const unsigned kin = *(const unsigned*)&qkv[base + D_];
  const float q0 = b2f((unsigned short)qin), q1 = b2f((unsigned short)(qin >> 16));
  const float k0 = b2f((unsigned short)kin), k1 = b2f((unsigned short)(kin >> 16));
  const float sc = 0.12751743f;  // log2(e)/sqrt(128): softmax in exp2 domain
  const float qo0 = (q0 * cs - q1 * sn) * sc, qo1 = (q1 * cs + q0 * sn) * sc;
  const float ko0 = (k0 * cs - k1 * sn), ko1 = (k1 * cs + k0 * sn);
  const long oo = ((long)(b * H_ + h) * L_ + l) * DH + 2 * i;
  *(unsigned*)&Qo[oo] = (unsigned)f2b(qo0) | ((unsigned)f2b(qo1) << 16);
  *(unsigned*)&Ko[oo] = (unsigned)f2b(ko0) | ((unsigned)f2b(ko1) << 16);
}

// ---------------- V pack into MFMA B-fragment tiles ----------------
__global__ __launch_bounds__(256)
void v_fragpack(const unsigned short* __restrict__ qkv,
                unsigned short* __restrict__ Vf) {
  const int lblk = blockIdx.x;  // L/64
  const int bh = blockIdx.y;    // B*H
  const int b = bh >> 4, h = bh & 15;
  __shared__ unsigned short tile[64 * 137];
  const int tid = threadIdx.x;
  const int l0 = lblk * 64;
#pragma unroll
  for (int j = 0; j < 4; ++j) {
    const int c = j * 256 + tid;
    const int row = c >> 4, col8 = c & 15;
    const us8 v = *(const us8*)&qkv[((long)b * L_ + l0 + row) * (3 * D_) +
                                    2 * D_ + h * DH + col8 * 8];
    unsigned short* dst = &tile[row * 137 + col8 * 8];
#pragma unroll
    for (int e = 0; e < 8; ++e) dst[e] = v[e];
  }
  __syncthreads();
#pragma unroll
  for (int j = 0; j < 4; ++j) {
    const int c = j * 256 + tid;
    const int k32l = c >> 9, t2 = (c >> 6) & 7, lane = c & 63;
    const int lo = lane & 15, hi = lane >> 4;
    us8 v;
#pragma unroll
    for (int e = 0; e < 8; ++e)
      v[e] = tile[(k32l * 32 + hi * 8 + e) * 137 + t2 * 16 + lo];
    *(us8*)&Vf[(((size_t)bh * 64 + lblk * 2 + k32l) * 8 + t2) * 512 + lane * 8] = v;
  }
}

// ---------------- causal flash attention: fold-paired q-tiles, swapped QK^T ----------------
__global__ __launch_bounds__(256, 2)
void flash_attn3(const unsigned short* __restrict__ Q,
                 const unsigned short* __restrict__ Kg,
                 const unsigned short* __restrict__ Vf,
                 unsigned short* __restrict__ Y) {
  const int p = blockIdx.x;  // 0..15
  const int tA = p, tB = (L_ / 64 - 1) - p;
  const int h = blockIdx.y, b = blockIdx.z;
  const int tid = threadIdx.x;
  const int wave = tid >> 6, lane = tid & 63;
  const int lo = lane & 15, hi = lane >> 4;
  const int swz = (lo & 7) << 4;
  const int qA = tA * 64 + wave * 16;
  const int qB = tB * 64 + wave * 16;
  const long hoff = ((long)(b * H_ + h)) * L_ * DH;
  const unsigned short* Qh = Q + hoff;
  const unsigned short* Kh = Kg + hoff;
  const unsigned short* Vfh = Vf + ((size_t)(b * H_ + h)) * (64 * 8 * 512);

  __shared__ unsigned short lK[2][64 * 128];
  __shared__ unsigned short pl[4][2][16 * 72];
  unsigned short* plA = &pl[wave][0][0];
  unsigned short* plB = &pl[wave][1][0];

  auto stage = [&](int bufi, int kv0s) {
    unsigned short* bk = &lK[bufi][0];
#pragma unroll
    for (int j = 0; j < 4; ++j) {
      const int c = j * 256 + tid;
      const int row = c >> 4;
      const int soff = ((c & 15) ^ (row & 7)) << 3;
      GLD16(Kh + (long)(kv0s + row) * DH + soff, &bk[(c & ~63) * 8]);
    }
  };

  bf16x8 qfA[4], qfB[4];
#pragma unroll
  for (int s = 0; s < 4; ++s) {
    qfA[s] = *(const bf16x8*)&Qh[(long)(qA + lo) * DH + s * 32 + hi * 8];
    qfB[s] = *(const bf16x8*)&Qh[(long)(qB + lo) * DH + s * 32 + hi * 8];
  }

  float mA = -INFINITY, lsA = 0.f, mB = -INFINITY, lsB = 0.f;
  f32x4 yA[8] = {}, yB[8] = {};

  auto softmax = [&](f32x4 (&st)[4], float& m, float& lsum, f32x4 (&yacc)[8],
                     unsigned short* plw, int qw, int kv0) {
    if (kv0 + 63 > qw) {
      const int d0 = qw + lo - kv0 - hi * 4;
#pragma unroll
      for (int t = 0; t < 4; ++t) {
        const int dt = d0 - t * 16;
#pragma unroll
        for (int r = 0; r < 4; ++r)
          if (r > dt) st[t][r] = -INFINITY;
      }
    }
    float tm0 = fmaxf(fmaxf(st[0][0], st[0][1]), fmaxf(st[0][2], st[0][3]));
    float tm1 = fmaxf(fmaxf(st[1][0], st[1][1]), fmaxf(st[1][2], st[1][3]));
    float tm2 = fmaxf(fmaxf(st[2][0], st[2][1]), fmaxf(st[2][2], st[2][3]));
    float tm3 = fmaxf(fmaxf(st[3][0], st[3][1]), fmaxf(st[3][2], st[3][3]));
    float rm = fmaxf(fmaxf(tm0, tm1), fmaxf(tm2, tm3));
    rm = fmaxf(rm, __shfl_xor(rm, 16));
    rm = fmaxf(rm, __shfl_xor(rm, 32));
    if (!__all(rm <= m + 8.f)) {
      const float mn = fmaxf(m, rm);
      const float alpha = exp2f(m - mn);
      m = mn;
      lsum *= alpha;
      float ar[4];
#pragma unroll
      for (int r = 0; r < 4; ++r) ar[r] = __shfl(alpha, hi * 4 + r);
#pragma unroll
      for (int t2 = 0; t2 < 8; ++t2)
#pragma unroll
        for (int r = 0; r < 4; ++r) yacc[t2][r] *= ar[r];
    }
    float rs = 0.f;
#pragma unroll
    for (int t = 0; t < 4; ++t) {
#pragma unroll
      for (int r2 = 0; r2 < 2; ++r2) {
        const float e0 = exp2f(st[t][2 * r2] - m);
        const float e1 = exp2f(st[t][2 * r2 + 1] - m);
        rs += e0 + e1;
        const unsigned short u0 = __builtin_bit_cast(unsigned short, (__bf16)e0);
        const unsigned short u1 = __builtin_bit_cast(unsigned short, (__bf16)e1);
        *(unsigned*)&plw[lo * 72 + t * 16 + hi * 4 + 2 * r2] =
            (unsigned)u0 | ((unsigned)u1 << 16);
      }
    }
    rs += __shfl_xor(rs, 16);
    rs += __shfl_xor(rs, 32);
    lsum += rs;
  };

  const int nIter = tB + 1;
  stage(0, 0);
  __syncthreads();

  for (int it = 0; it < nIter; ++it) {
    const int kv0 = it * 64;
    const bool aAct = (it <= tA);
    if (it + 1 < nIter) stage((it + 1) & 1, kv0 + 64);
    const char* bkc = (const char*)&lK[it & 1][0];
    f32x4 stA[4] = {}, stB[4] = {};
    if (aAct) {
#pragma unroll
      for (int s = 0; s < 4; ++s) {
        const int inner = (lo * 256 + s * 64 + hi * 16) ^ swz;
#pragma unroll
        for (int t = 0; t < 4; ++t) {
          const bf16x8 kf = *(const bf16x8*)(bkc + t * 4096 + inner);
          stA[t] = __builtin_amdgcn_mfma_f32_16x16x32_bf16(kf, qfA[s], stA[t], 0, 0, 0);
          stB[t] = __builtin_amdgcn_mfma_f32_16x16x32_bf16(kf, qfB[s], stB[t], 0, 0, 0);
        }
      }
    } else {
#pragma unroll
      for (int s = 0; s < 4; ++s) {
        const int inner = (lo * 256 + s * 64 + hi * 16) ^ swz;
#pragma unroll
        for (int t = 0; t < 4; ++t) {
          const bf16x8 kf = *(const bf16x8*)(bkc + t * 4096 + inner);
          stB[t] = __builtin_amdgcn_mfma_f32_16x16x32_bf16(kf, qfB[s], stB[t], 0, 0, 0);
        }
      }
    }
    if (aAct) softmax(stA, mA, lsA, yA, plA, qA, kv0);
    softmax(stB, mB, lsB, yB, plB, qB, kv0);
    const unsigned short* vbase = Vfh + (size_t)(it * 16) * 512 + lane * 8;
#pragma unroll
    for (int kt = 0; kt < 2; ++kt) {
      bf16x8 vf[8];
#pragma unroll
      for (int t2 = 0; t2 < 8; ++t2)
        vf[t2] = *(const bf16x8*)(vbase + (size_t)(kt * 8 + t2) * 512);
      const bf16x8 pfB = *(const bf16x8*)&plB[lo * 72 + kt * 32 + hi * 8];
#pragma unroll
      for (int t2 = 0; t2 < 8; ++t2)
        yB[t2] = __builtin_amdgcn_mfma_f32_16x16x32_bf16(pfB, vf[t2], yB[t2], 0, 0, 0);
      if (aAct) {
        const bf16x8 pfA = *(const bf16x8*)&plA[lo * 72 + kt * 32 + hi * 8];
#pragma unroll
        for (int t2 = 0; t2 < 8; ++t2)
          yA[t2] = __builtin_amdgcn_mfma_f32_16x16x32_bf16(pfA, vf[t2], yA[t2], 0, 0, 0);
      }
    }
    __syncthreads();
  }

  auto wout = [&](f32x4 (&yacc)[8], float lsum, int qw) {
    const float inv = 1.f / lsum;
    float ir[4];
#pragma unroll
    for (int r = 0; r < 4; ++r) ir[r] = __shfl(inv, hi * 4 + r);
#pragma unroll
    for (int r = 0; r < 4; ++r) {
      const long row = qw + hi * 4 + r;
      unsigned short* yrow = Y + ((long)b * L_ + row) * D_ + h * DH;
#pragma unroll
      for (int t2 = 0; t2 < 8; ++t2)
        yrow[t2 * 16 + lo] = f2b(yacc[t2][r] * ir[r]);
    }
  };
  wout(yA, lsA, qA);
  wout(yB, lsB, qB);
}

extern "C" void kernel_launch(void* const* d_in, const int* in_sizes, int n_in,
                              void* d_out, int out_size, void* d_ws, size_t ws_size,
                              hipStream_t stream) {
  const float* x = (const float*)d_in[0];
  const float* wqkv = (const float*)d_in[1];
  const float* wo = (const float*)d_in[2];
  float* out = (float*)d_out;

  unsigned short* ws = (unsigned short*)d_ws;
  const size_t N_X = (size_t)B_ * L_ * D_;
  const size_t N_WQKV = (size_t)3 * D_ * D_;
  const size_t N_WO = (size_t)D_ * D_;
  const size_t N_QKV = (size_t)B_ * L_ * 3 * D_;
  const size_t N_HEAD = (size_t)B_ * H_ * L_ * DH;
  unsigned short* xb = ws;
  unsigned short* wqkb = xb + N_X;
  unsigned short* wob = wqkb + N_WQKV;
  unsigned short* qkv = wob + N_WO;
  unsigned short* Qb = qkv + N_QKV;
  unsigned short* Kb = Qb + N_HEAD;
  unsigned short* Vf = Kb + N_HEAD;
  unsigned short* Yb = Vf + N_HEAD;
  const size_t need = (size_t)(Yb + N_HEAD - ws) * sizeof(unsigned short);
  if (ws_size < need) return;

  f32_to_bf16<<<2048, 256, 0, stream>>>(x, xb, (int)(N_X / 4));
  f32_to_bf16<<<2048, 256, 0, stream>>>(wqkv, wqkb, (int)(N_WQKV / 4));
  f32_to_bf16<<<2048, 256, 0, stream>>>(wo, wob, (int)(N_WO / 4));

  // qkv = x @ W_qkv^T : M=4096, N=6144, K=2048 -> 16x24 = 384 blocks
  gemm8p<true><<<(B_ * L_ / 256) * (3 * D_ / 256), 512, 0, stream>>>(
      xb, wqkb, qkv, B_ * L_, 3 * D_, D_);

  rope_qk<<<(B_ * H_ * L_ * 64) / 256, 256, 0, stream>>>(qkv, Qb, Kb);
  v_fragpack<<<dim3(L_ / 64, B_ * H_), 256, 0, stream>>>(qkv, Vf);

  flash_attn3<<<dim3(16, H_, B_), 256, 0, stream>>>(Qb, Kb, Vf, Yb);

  // out = y @ W_o^T : M=4096, N=2048, K=2048 -> 16x8 = 128 blocks
  gemm8p<false><<<(B_ * L_ / 256) * (D_ / 256), 512, 0, stream>>>(
      Yb, wob, out, B_ * L_, D_, D_);
}